// Round 9
// baseline (2134.975 us; speedup 1.0000x reference)
//
#include <hip/hip_runtime.h>
#include <hip/hip_fp16.h>

typedef unsigned int u32;
typedef _Float16 half2v __attribute__((ext_vector_type(2)));
typedef _Float16 half4v __attribute__((ext_vector_type(4)));
typedef _Float16 half8v __attribute__((ext_vector_type(8)));
typedef float f32x4 __attribute__((ext_vector_type(4)));

#define T_DIM 1024
#define B_DIM 256
#define H_DIM 256
#define G_DIM 768   // 3*H

// ---------------------------------------------------------------------------
// prep: transpose + f32->f16 for both weight matrices.
// ---------------------------------------------------------------------------
__global__ void prep_kernel(const float* __restrict__ Wi,
                            const float* __restrict__ Wh,
                            _Float16* __restrict__ WiT,
                            _Float16* __restrict__ WhT) {
  int idx = blockIdx.x * 256 + threadIdx.x;
  const int total = G_DIM * H_DIM;
  const float* src = Wi;
  _Float16* dst = WiT;
  if (idx >= total) { idx -= total; src = Wh; dst = WhT; }
  int g = idx >> 8;     // 0..767
  int k = idx & 255;    // 0..255
  dst[idx] = (_Float16)src[(size_t)k * G_DIM + g];
}

// ---------------------------------------------------------------------------
// Phase 1: gi[M][768] (f16) = ins[M][256] (f32) @ Wi + bi, via MFMA f16.
// (unchanged; target after the scan is fixed)
// ---------------------------------------------------------------------------
#define BM 128
#define BN 128
#define BK 64
#define LDK 72   // padded f16 leading dim

__global__ __launch_bounds__(256, 2) void gemm_gi_kernel(
    const float* __restrict__ A,       // ins [M][256]
    const _Float16* __restrict__ BT,   // WiT [768][256]
    const float* __restrict__ bias,    // bi [768] f32
    _Float16* __restrict__ C)          // gi [M][768]
{
  __shared__ _Float16 As[BM * LDK];
  __shared__ _Float16 Bs[BN * LDK];

  const int tid  = threadIdx.x;
  const int lane = tid & 63;
  const int wid  = tid >> 6;
  const int wr   = wid >> 1;
  const int wc   = wid & 1;

  const int id   = blockIdx.x;
  const int xcd  = id & 7;
  const int slot = id >> 3;
  const int nt   = slot % 6;
  const int mt   = (slot / 6) * 8 + xcd;
  const int m0 = mt * BM;
  const int n0 = nt * BN;

  f32x4 acc[4][4] = {};

  for (int kt = 0; kt < H_DIM; kt += BK) {
#pragma unroll
    for (int i = 0; i < 8; ++i) {
      int c   = tid + i * 256;
      int row = c >> 4;
      int kc  = (c & 15) << 2;
      const float4 v = *(const float4*)(A + (size_t)(m0 + row) * H_DIM + kt + kc);
      half4v h;
      h.x = (_Float16)v.x; h.y = (_Float16)v.y;
      h.z = (_Float16)v.z; h.w = (_Float16)v.w;
      *(half4v*)(&As[row * LDK + kc]) = h;
    }
#pragma unroll
    for (int i = 0; i < 8; ++i) {
      int c   = tid + i * 256;
      int row = c >> 4;
      int kc  = (c & 15) << 2;
      half4v v = *(const half4v*)(BT + (size_t)(n0 + row) * H_DIM + kt + kc);
      *(half4v*)(&Bs[row * LDK + kc]) = v;
    }
    __syncthreads();

#pragma unroll
    for (int kk = 0; kk < 2; ++kk) {
      half8v af[4], bf[4];
#pragma unroll
      for (int m = 0; m < 4; ++m)
        af[m] = *(const half8v*)(&As[(wr*64 + m*16 + (lane & 15)) * LDK + kk*32 + (lane >> 4)*8]);
#pragma unroll
      for (int n = 0; n < 4; ++n)
        bf[n] = *(const half8v*)(&Bs[(wc*64 + n*16 + (lane & 15)) * LDK + kk*32 + (lane >> 4)*8]);
#pragma unroll
      for (int m = 0; m < 4; ++m)
#pragma unroll
        for (int n = 0; n < 4; ++n)
          acc[m][n] = __builtin_amdgcn_mfma_f32_16x16x32_f16(af[m], bf[n], acc[m][n], 0, 0, 0);
    }
    __syncthreads();
  }

#pragma unroll
  for (int n = 0; n < 4; ++n) {
    const int col = n0 + wc*64 + n*16 + (lane & 15);
    const float bv = bias[col];
#pragma unroll
    for (int m = 0; m < 4; ++m) {
#pragma unroll
      for (int q = 0; q < 4; ++q) {
        const int row = m0 + wr*64 + m*16 + (lane >> 4)*4 + q;
        C[(size_t)row * G_DIM + col] = (_Float16)(acc[m][n][q] + bv);
      }
    }
  }
}

// ---------------------------------------------------------------------------
// Phase 2: persistent GRU scan — QUAD k-split dot2.
// 256 wgs x 1024 threads (16 waves, 4 waves/SIMD, HARD 128-reg cap via
// __launch_bounds__(1024,4)). Thread quad (4 lanes) owns output j; lane qt
// holds all 3 gate columns over QUARTER qt of k = 96 persistent dwords
// (r3..r8 lesson: 192-dword arrays get AGPR-homed -> per-use copy tax;
// 96 + ~30 working fits the 128 cap with the weights as the hot set).
// 4 waves/SIMD gives the cross-wave latency hiding 2 phase-locked waves
// couldn't. Dot floor: 4 waves x 96 dot2 x 2cyc = 768 cyc/SIMD/step.
// LDS: quarter qt of h at byte qt*144 (stride 144 -> the 4 broadcast
// addresses hit 16 disjoint banks for every chunk: banks {4c,4c+4,4c+8,
// 4c+12}+0..3). Quad combine: shfl_xor 1,2 (DPP). gi prefetched a full
// step ahead. Double-buffered h, ONE lgkmcnt-only barrier per step.
// ---------------------------------------------------------------------------
__device__ __forceinline__ float sigmoidf_fast(float x) {
  return __builtin_amdgcn_rcpf(1.f + __expf(-x));
}
__device__ __forceinline__ float tanhf_fast(float x) {
  return 1.f - 2.f * __builtin_amdgcn_rcpf(__expf(2.f * x) + 1.f);
}

__device__ __forceinline__ void dot2v(float& acc, u32 w, u32 h) {
  asm("v_dot2_f32_f16 %0, %1, %2, %0" : "+v"(acc) : "v"(w), "v"(h));
}

// 12 dot2 consuming one uint4 h-chunk (8 h values) against 3 gates
#define DOT12(HV, c)                          \
  dot2v(aR, wR[4*(c)  ], (HV).x);             \
  dot2v(aZ, wZ[4*(c)  ], (HV).x);             \
  dot2v(aN, wN[4*(c)  ], (HV).x);             \
  dot2v(aR, wR[4*(c)+1], (HV).y);             \
  dot2v(aZ, wZ[4*(c)+1], (HV).y);             \
  dot2v(aN, wN[4*(c)+1], (HV).y);             \
  dot2v(aR, wR[4*(c)+2], (HV).z);             \
  dot2v(aZ, wZ[4*(c)+2], (HV).z);             \
  dot2v(aN, wN[4*(c)+2], (HV).z);             \
  dot2v(aR, wR[4*(c)+3], (HV).w);             \
  dot2v(aZ, wZ[4*(c)+3], (HV).w);             \
  dot2v(aN, wN[4*(c)+3], (HV).w);

// zero-cost dependency tie: caps ds_read hoisting (live h regs = 8 dwords)
#define TIE() asm("" : "+v"(z) : "v"(aR), "v"(aZ), "v"(aN))

#define QSTRIDE 144   // bytes per k-quarter region in hbuf

__global__ __launch_bounds__(1024, 4) void gru_scan_kernel(
    const _Float16* __restrict__ WhT,   // [768][256]
    const _Float16* __restrict__ gi,    // [T][B][768] f16
    const int* __restrict__ resets,     // [T][B] int32
    const float* __restrict__ h0,       // [B][256]
    const float* __restrict__ bhn,      // [256]
    float* __restrict__ ys)             // [T][B][256]
{
  const int b  = blockIdx.x;
  const int s  = threadIdx.x;   // 0..1023
  const int j  = s >> 2;        // output index 0..255
  const int qt = s & 3;         // k-quarter: [qt*64, qt*64+64)

  __shared__ __align__(16) char hbuf[2][4 * QSTRIDE];

  // ---- persistent weights: 3 gates x 32 dwords (quarter of k) ----
  u32 wR[32], wZ[32], wN[32];
  {
    const uint4* pR = (const uint4*)(WhT + (size_t)j         * H_DIM + qt * 64);
    const uint4* pZ = (const uint4*)(WhT + (size_t)(j + 256) * H_DIM + qt * 64);
    const uint4* pN = (const uint4*)(WhT + (size_t)(j + 512) * H_DIM + qt * 64);
#pragma unroll
    for (int i = 0; i < 8; ++i) {
      uint4 v = pR[i]; wR[4*i]=v.x; wR[4*i+1]=v.y; wR[4*i+2]=v.z; wR[4*i+3]=v.w;
    }
#pragma unroll
    for (int i = 0; i < 8; ++i) {
      uint4 v = pZ[i]; wZ[4*i]=v.x; wZ[4*i+1]=v.y; wZ[4*i+2]=v.z; wZ[4*i+3]=v.w;
    }
#pragma unroll
    for (int i = 0; i < 8; ++i) {
      uint4 v = pN[i]; wN[4*i]=v.x; wN[4*i+1]=v.y; wN[4*i+2]=v.z; wN[4*i+3]=v.w;
    }
  }

  const float bn = bhn[j];

  // roles within the quad (one carry writer, one ys writer per j)
  const int region = j >> 6;                     // which quarter owns h_j
  const int carry_writer = (qt == region);
  const int ys_writer    = (qt == ((region + 1) & 3));
  const int waddr = region * QSTRIDE + (j & 63) * 2;   // byte addr of h_j

  // ---- init carry (masked by resets[0]) ----
  float hprev;
  {
    const int r0 = resets[b];
    hprev = r0 ? 0.f : h0[(size_t)b * H_DIM + j];
    if (carry_writer) *(_Float16*)(&hbuf[0][waddr]) = (_Float16)hprev;
  }
  __syncthreads();

  const _Float16* gbase = gi + (size_t)b * G_DIM + j;
  float* yp = ys + (size_t)b * H_DIM + j;

  // preload gi for t=0
  float gcR = (float)gbase[0];
  float gcZ = (float)gbase[256];
  float gcN = (float)gbase[512];

  int p = 0;
  for (int t = 0; t < T_DIM; ++t) {
    // ---- prefetch gi(t+1) (clamped; consumed NEXT iteration) ----
    const int tn = (t + 1 < T_DIM) ? (t + 1) : (T_DIM - 1);
    const _Float16* gp = gbase + (size_t)tn * (B_DIM * G_DIM);
    const float gnR = (float)gp[0];
    const float gnZ = (float)gp[256];
    const float gnN = (float)gp[512];
    const int rstn = (t + 1 < T_DIM) ? resets[tn * B_DIM + b] : 0;

    // ---- 96 dot2 over this lane's k-quarter; 2-deep rotating h pipe ----
    float aR = 0.f, aZ = 0.f, aN = 0.f;
    int z = 0;
    const char* hb = &hbuf[p][qt * QSTRIDE];

    uint4 hA = *(const uint4*)(hb);
    uint4 hB = *(const uint4*)(hb + 16);
    DOT12(hA, 0); TIE(); hA = *(const uint4*)(hb + z + 32);
    DOT12(hB, 1); TIE(); hB = *(const uint4*)(hb + z + 48);
    DOT12(hA, 2); TIE(); hA = *(const uint4*)(hb + z + 64);
    DOT12(hB, 3); TIE(); hB = *(const uint4*)(hb + z + 80);
    DOT12(hA, 4); TIE(); hA = *(const uint4*)(hb + z + 96);
    DOT12(hB, 5); TIE(); hB = *(const uint4*)(hb + z + 112);
    DOT12(hA, 6);
    DOT12(hB, 7);

    // ---- quad combine (DPP) — all 4 lanes end with full sums ----
    aR += __shfl_xor(aR, 1);  aR += __shfl_xor(aR, 2);
    aZ += __shfl_xor(aZ, 1);  aZ += __shfl_xor(aZ, 2);
    aN += __shfl_xor(aN, 1);  aN += __shfl_xor(aN, 2);

    // ---- activation (redundant in all 4 lanes) ----
    const float r  = sigmoidf_fast(aR + gcR);
    const float zg = sigmoidf_fast(aZ + gcZ);
    const float n  = tanhf_fast(gcN + r * (aN + bn));
    const float hn = (1.f - zg) * n + zg * hprev;

    const float hx = rstn ? 0.f : hn;    // mask BEFORE carry store
    if (carry_writer) {
      *(_Float16*)(&hbuf[p ^ 1][waddr]) = (_Float16)hx;
    } else if (ys_writer) {
      yp[(size_t)t * (B_DIM * H_DIM)] = hn;
    }
    hprev = hx;
    gcR = gnR; gcZ = gnZ; gcN = gnN;

    // drain LDS (h write) but NOT vmcnt (ys store stays in flight)
    asm volatile("s_waitcnt lgkmcnt(0)\n\ts_barrier" ::: "memory");
    p ^= 1;
  }
}

// sentinel: distinctive failure signature if workspace is too small
__global__ void sentinel_kernel(float* out, int n) {
  int i = blockIdx.x * 256 + threadIdx.x;
  if (i < n) out[i] = 12345.0f;
}

// ---------------------------------------------------------------------------
extern "C" void kernel_launch(void* const* d_in, const int* in_sizes, int n_in,
                              void* d_out, int out_size, void* d_ws, size_t ws_size,
                              hipStream_t stream) {
  const float* ins    = (const float*)d_in[0];
  const int*   resets = (const int*)d_in[1];
  const float* h0     = (const float*)d_in[2];
  const float* Wi     = (const float*)d_in[3];
  const float* bi     = (const float*)d_in[4];
  const float* Wh     = (const float*)d_in[5];
  const float* bhn    = (const float*)d_in[6];
  float* ys = (float*)d_out;

  const size_t wbytes  = (size_t)G_DIM * H_DIM * 2;            // 393,216
  const size_t gibytes = (size_t)T_DIM * B_DIM * G_DIM * 2;    // 402,653,184
  const size_t need = 2 * wbytes + gibytes;
  if (ws_size < need) {
    sentinel_kernel<<<(out_size + 255) / 256, 256, 0, stream>>>(ys, out_size);
    return;
  }

  char* ws = (char*)d_ws;
  _Float16* WiT = (_Float16*)ws;
  _Float16* WhT = (_Float16*)(ws + wbytes);
  _Float16* gi  = (_Float16*)(ws + 2 * wbytes);

  prep_kernel<<<(2 * G_DIM * H_DIM) / 256, 256, 0, stream>>>(Wi, Wh, WiT, WhT);

  const int M = T_DIM * B_DIM;                 // 262144
  const int nblocks = (M / BM) * (G_DIM / BN); // 12288
  gemm_gi_kernel<<<nblocks, 256, 0, stream>>>(ins, WiT, bi, gi);

  gru_scan_kernel<<<B_DIM, 1024, 0, stream>>>(WhT, gi, resets, h0, bhn, ys);
}

// Round 10
// 1843.181 us; speedup vs baseline: 1.1583x; 1.1583x over previous
//
#include <hip/hip_runtime.h>
#include <hip/hip_fp16.h>

typedef unsigned int u32;
typedef _Float16 half2v __attribute__((ext_vector_type(2)));
typedef _Float16 half4v __attribute__((ext_vector_type(4)));
typedef _Float16 half8v __attribute__((ext_vector_type(8)));
typedef float f32x4 __attribute__((ext_vector_type(4)));

#define T_DIM 1024
#define B_DIM 256
#define H_DIM 256
#define G_DIM 768   // 3*H

// ---------------------------------------------------------------------------
// prep: transpose + f32->f16 for both weight matrices.
// ---------------------------------------------------------------------------
__global__ void prep_kernel(const float* __restrict__ Wi,
                            const float* __restrict__ Wh,
                            _Float16* __restrict__ WiT,
                            _Float16* __restrict__ WhT) {
  int idx = blockIdx.x * 256 + threadIdx.x;
  const int total = G_DIM * H_DIM;
  const float* src = Wi;
  _Float16* dst = WiT;
  if (idx >= total) { idx -= total; src = Wh; dst = WhT; }
  int g = idx >> 8;     // 0..767
  int k = idx & 255;    // 0..255
  dst[idx] = (_Float16)src[(size_t)k * G_DIM + g];
}

// ---------------------------------------------------------------------------
// Phase 1: gi[M][768] (f16) = ins[M][256] (f32) @ Wi + bi, via MFMA f16.
// ROUND 10: column-interleaved B-frags. B tile n covers cols {4*lc + n}
// (permuted LDS row n*32 + wc*16 + lc, bijective), so each thread owns 4
// ADJACENT output cols -> epilogue is 16 coalesced 8B stores (was 64 x 2B
// scattered) and bias is one float4 load.
// ---------------------------------------------------------------------------
#define BM 128
#define BN 128
#define BK 64
#define LDK 72   // padded f16 leading dim

__global__ __launch_bounds__(256, 2) void gemm_gi_kernel(
    const float* __restrict__ A,       // ins [M][256]
    const _Float16* __restrict__ BT,   // WiT [768][256]
    const float* __restrict__ bias,    // bi [768] f32
    _Float16* __restrict__ C)          // gi [M][768]
{
  __shared__ _Float16 As[BM * LDK];
  __shared__ _Float16 Bs[BN * LDK];

  const int tid  = threadIdx.x;
  const int lane = tid & 63;
  const int lc   = lane & 15;
  const int lg   = lane >> 4;
  const int wid  = tid >> 6;
  const int wr   = wid >> 1;
  const int wc   = wid & 1;

  const int id   = blockIdx.x;
  const int xcd  = id & 7;
  const int slot = id >> 3;
  const int nt   = slot % 6;
  const int mt   = (slot / 6) * 8 + xcd;
  const int m0 = mt * BM;
  const int n0 = nt * BN;

  f32x4 acc[4][4] = {};

  for (int kt = 0; kt < H_DIM; kt += BK) {
#pragma unroll
    for (int i = 0; i < 8; ++i) {
      int c   = tid + i * 256;
      int row = c >> 4;
      int kc  = (c & 15) << 2;
      const float4 v = *(const float4*)(A + (size_t)(m0 + row) * H_DIM + kt + kc);
      half4v h;
      h.x = (_Float16)v.x; h.y = (_Float16)v.y;
      h.z = (_Float16)v.z; h.w = (_Float16)v.w;
      *(half4v*)(&As[row * LDK + kc]) = h;
    }
#pragma unroll
    for (int i = 0; i < 8; ++i) {
      int c   = tid + i * 256;
      int row = c >> 4;                       // block-local col 0..127
      int kc  = (c & 15) << 2;
      half4v v = *(const half4v*)(BT + (size_t)(n0 + row) * H_DIM + kt + kc);
      int rowp = (row & 3) * 32 + (row >> 2); // interleave perm (bijective)
      *(half4v*)(&Bs[rowp * LDK + kc]) = v;
    }
    __syncthreads();

#pragma unroll
    for (int kk = 0; kk < 2; ++kk) {
      half8v af[4], bf[4];
#pragma unroll
      for (int m = 0; m < 4; ++m)
        af[m] = *(const half8v*)(&As[(wr*64 + m*16 + lc) * LDK + kk*32 + lg*8]);
#pragma unroll
      for (int n = 0; n < 4; ++n)
        bf[n] = *(const half8v*)(&Bs[(n*32 + wc*16 + lc) * LDK + kk*32 + lg*8]);
#pragma unroll
      for (int m = 0; m < 4; ++m)
#pragma unroll
        for (int n = 0; n < 4; ++n)
          acc[m][n] = __builtin_amdgcn_mfma_f32_16x16x32_f16(af[m], bf[n], acc[m][n], 0, 0, 0);
    }
    __syncthreads();
  }

  // epilogue: thread owns cols n0 + wc*64 + 4*lc + [0..3] for its 16 rows
  const int cbase = n0 + wc*64 + 4*lc;
  const float4 bv4 = *(const float4*)(bias + cbase);
#pragma unroll
  for (int m = 0; m < 4; ++m) {
#pragma unroll
    for (int q = 0; q < 4; ++q) {
      const int row = m0 + wr*64 + m*16 + lg*4 + q;
      half4v o;
      o[0] = (_Float16)(acc[m][0][q] + bv4.x);
      o[1] = (_Float16)(acc[m][1][q] + bv4.y);
      o[2] = (_Float16)(acc[m][2][q] + bv4.z);
      o[3] = (_Float16)(acc[m][3][q] + bv4.w);
      *(half4v*)(&C[(size_t)row * G_DIM + cbase]) = o;
    }
  }
}

// ---------------------------------------------------------------------------
// Phase 2: persistent GRU scan — QUAD k-split dot2 with FUSED asm chunks.
// 256 wgs x 1024 threads (16 waves, 4 waves/SIMD, 128-reg budget).
// Round-9 diagnosis: accumulators ping-ponged AGPR<->VGPR (3 inst per dot2,
// 351 inst/wave/step measured) because each dot2 was a separate asm
// statement; and TIE deps serialized h loads behind accumulator results.
// Fixes: (1) one asm block per 12-dot chunk (accs pinned in VGPR inside);
// (2) loads decoupled from accs, 2 rotating h regs + sched_barrier spacers;
// (3) gi(t+1)/reset loads moved AFTER the dots (peak pressure ~122 <= 128).
// AGPR-homed weight copies (~60/step, the 50/50 file split) remain — priced.
// ---------------------------------------------------------------------------
__device__ __forceinline__ float sigmoidf_fast(float x) {
  return __builtin_amdgcn_rcpf(1.f + __expf(-x));
}
__device__ __forceinline__ float tanhf_fast(float x) {
  return 1.f - 2.f * __builtin_amdgcn_rcpf(__expf(2.f * x) + 1.f);
}

// 12 dot2 as ONE asm block: accs cannot leave VGPRs mid-chunk.
// %0-%2 accs, %3-%6 wR, %7-%10 wZ, %11-%14 wN, %15-%18 h dwords.
#define DOT12(HV, c)                                                  \
  asm("v_dot2_f32_f16 %0, %3, %15, %0\n\t"                            \
      "v_dot2_f32_f16 %1, %7, %15, %1\n\t"                            \
      "v_dot2_f32_f16 %2, %11, %15, %2\n\t"                           \
      "v_dot2_f32_f16 %0, %4, %16, %0\n\t"                            \
      "v_dot2_f32_f16 %1, %8, %16, %1\n\t"                            \
      "v_dot2_f32_f16 %2, %12, %16, %2\n\t"                           \
      "v_dot2_f32_f16 %0, %5, %17, %0\n\t"                            \
      "v_dot2_f32_f16 %1, %9, %17, %1\n\t"                            \
      "v_dot2_f32_f16 %2, %13, %17, %2\n\t"                           \
      "v_dot2_f32_f16 %0, %6, %18, %0\n\t"                            \
      "v_dot2_f32_f16 %1, %10, %18, %1\n\t"                           \
      "v_dot2_f32_f16 %2, %14, %18, %2"                               \
      : "+v"(aR), "+v"(aZ), "+v"(aN)                                  \
      : "v"(wR[4*(c)]), "v"(wR[4*(c)+1]), "v"(wR[4*(c)+2]), "v"(wR[4*(c)+3]), \
        "v"(wZ[4*(c)]), "v"(wZ[4*(c)+1]), "v"(wZ[4*(c)+2]), "v"(wZ[4*(c)+3]), \
        "v"(wN[4*(c)]), "v"(wN[4*(c)+1]), "v"(wN[4*(c)+2]), "v"(wN[4*(c)+3]), \
        "v"((HV).x), "v"((HV).y), "v"((HV).z), "v"((HV).w))

#define SB() __builtin_amdgcn_sched_barrier(0)

#define QSTRIDE 144   // bytes per k-quarter region (r9-proven: 0 conflicts)

__global__ __launch_bounds__(1024, 4) void gru_scan_kernel(
    const _Float16* __restrict__ WhT,   // [768][256]
    const _Float16* __restrict__ gi,    // [T][B][768] f16
    const int* __restrict__ resets,     // [T][B] int32
    const float* __restrict__ h0,       // [B][256]
    const float* __restrict__ bhn,      // [256]
    float* __restrict__ ys)             // [T][B][256]
{
  const int b  = blockIdx.x;
  const int s  = threadIdx.x;   // 0..1023
  const int j  = s >> 2;        // output index 0..255
  const int qt = s & 3;         // k-quarter: [qt*64, qt*64+64)

  __shared__ __align__(16) char hbuf[2][4 * QSTRIDE];

  // ---- persistent weights: 3 gates x 32 dwords (quarter of k) ----
  u32 wR[32], wZ[32], wN[32];
  {
    const uint4* pR = (const uint4*)(WhT + (size_t)j         * H_DIM + qt * 64);
    const uint4* pZ = (const uint4*)(WhT + (size_t)(j + 256) * H_DIM + qt * 64);
    const uint4* pN = (const uint4*)(WhT + (size_t)(j + 512) * H_DIM + qt * 64);
#pragma unroll
    for (int i = 0; i < 8; ++i) {
      uint4 v = pR[i]; wR[4*i]=v.x; wR[4*i+1]=v.y; wR[4*i+2]=v.z; wR[4*i+3]=v.w;
    }
#pragma unroll
    for (int i = 0; i < 8; ++i) {
      uint4 v = pZ[i]; wZ[4*i]=v.x; wZ[4*i+1]=v.y; wZ[4*i+2]=v.z; wZ[4*i+3]=v.w;
    }
#pragma unroll
    for (int i = 0; i < 8; ++i) {
      uint4 v = pN[i]; wN[4*i]=v.x; wN[4*i+1]=v.y; wN[4*i+2]=v.z; wN[4*i+3]=v.w;
    }
  }

  const float bn = bhn[j];

  // roles within the quad (one carry writer, one ys writer per j)
  const int region = j >> 6;
  const int carry_writer = (qt == region);
  const int ys_writer    = (qt == ((region + 1) & 3));
  const int waddr = region * QSTRIDE + (j & 63) * 2;

  // ---- init carry (masked by resets[0]) ----
  float hprev;
  {
    const int r0 = resets[b];
    hprev = r0 ? 0.f : h0[(size_t)b * H_DIM + j];
    if (carry_writer) *(_Float16*)(&hbuf[0][waddr]) = (_Float16)hprev;
  }
  __syncthreads();

  const _Float16* gbase = gi + (size_t)b * G_DIM + j;
  float* yp = ys + (size_t)b * H_DIM + j;

  // preload gi for t=0
  float gcR = (float)gbase[0];
  float gcZ = (float)gbase[256];
  float gcN = (float)gbase[512];

  int p = 0;
  for (int t = 0; t < T_DIM; ++t) {
    // ---- 96 dot2 in 8 fused chunks; 2 rotating h regs, SB spacers ----
    float aR = 0.f, aZ = 0.f, aN = 0.f;
    const char* hb = &hbuf[p][qt * QSTRIDE];

    uint4 hA = *(const uint4*)(hb);
    uint4 hB = *(const uint4*)(hb + 16);
    DOT12(hA, 0);
    SB();
    hA = *(const uint4*)(hb + 32);
    DOT12(hB, 1);
    SB();
    hB = *(const uint4*)(hb + 48);
    DOT12(hA, 2);
    SB();
    hA = *(const uint4*)(hb + 64);
    DOT12(hB, 3);
    SB();
    hB = *(const uint4*)(hb + 80);
    DOT12(hA, 4);
    SB();
    hA = *(const uint4*)(hb + 96);
    DOT12(hB, 5);
    SB();
    hB = *(const uint4*)(hb + 112);
    DOT12(hA, 6);
    DOT12(hB, 7);

    // ---- gi(t+1)/reset prefetch AFTER dots (cuts peak pressure in dots;
    //      latency covered by epilogue + barrier + next step's dots) ----
    const int tn = (t + 1 < T_DIM) ? (t + 1) : (T_DIM - 1);
    const _Float16* gp = gbase + (size_t)tn * (B_DIM * G_DIM);
    const float gnR = (float)gp[0];
    const float gnZ = (float)gp[256];
    const float gnN = (float)gp[512];
    const int rstn = (t + 1 < T_DIM) ? resets[tn * B_DIM + b] : 0;

    // ---- quad combine (DPP) ----
    aR += __shfl_xor(aR, 1);  aR += __shfl_xor(aR, 2);
    aZ += __shfl_xor(aZ, 1);  aZ += __shfl_xor(aZ, 2);
    aN += __shfl_xor(aN, 1);  aN += __shfl_xor(aN, 2);

    // ---- activation (redundant in all 4 lanes) ----
    const float r  = sigmoidf_fast(aR + gcR);
    const float zg = sigmoidf_fast(aZ + gcZ);
    const float n  = tanhf_fast(gcN + r * (aN + bn));
    const float hn = (1.f - zg) * n + zg * hprev;

    const float hx = rstn ? 0.f : hn;    // mask BEFORE carry store
    if (carry_writer) {
      *(_Float16*)(&hbuf[p ^ 1][waddr]) = (_Float16)hx;
    } else if (ys_writer) {
      yp[(size_t)t * (B_DIM * H_DIM)] = hn;
    }
    hprev = hx;
    gcR = gnR; gcZ = gnZ; gcN = gnN;

    // drain LDS (h write) but NOT vmcnt (ys store stays in flight)
    asm volatile("s_waitcnt lgkmcnt(0)\n\ts_barrier" ::: "memory");
    p ^= 1;
  }
}

// sentinel: distinctive failure signature if workspace is too small
__global__ void sentinel_kernel(float* out, int n) {
  int i = blockIdx.x * 256 + threadIdx.x;
  if (i < n) out[i] = 12345.0f;
}

// ---------------------------------------------------------------------------
extern "C" void kernel_launch(void* const* d_in, const int* in_sizes, int n_in,
                              void* d_out, int out_size, void* d_ws, size_t ws_size,
                              hipStream_t stream) {
  const float* ins    = (const float*)d_in[0];
  const int*   resets = (const int*)d_in[1];
  const float* h0     = (const float*)d_in[2];
  const float* Wi     = (const float*)d_in[3];
  const float* bi     = (const float*)d_in[4];
  const float* Wh     = (const float*)d_in[5];
  const float* bhn    = (const float*)d_in[6];
  float* ys = (float*)d_out;

  const size_t wbytes  = (size_t)G_DIM * H_DIM * 2;            // 393,216
  const size_t gibytes = (size_t)T_DIM * B_DIM * G_DIM * 2;    // 402,653,184
  const size_t need = 2 * wbytes + gibytes;
  if (ws_size < need) {
    sentinel_kernel<<<(out_size + 255) / 256, 256, 0, stream>>>(ys, out_size);
    return;
  }

  char* ws = (char*)d_ws;
  _Float16* WiT = (_Float16*)ws;
  _Float16* WhT = (_Float16*)(ws + wbytes);
  _Float16* gi  = (_Float16*)(ws + 2 * wbytes);

  prep_kernel<<<(2 * G_DIM * H_DIM) / 256, 256, 0, stream>>>(Wi, Wh, WiT, WhT);

  const int M = T_DIM * B_DIM;                 // 262144
  const int nblocks = (M / BM) * (G_DIM / BN); // 12288
  gemm_gi_kernel<<<nblocks, 256, 0, stream>>>(ins, WiT, bi, gi);

  gru_scan_kernel<<<B_DIM, 1024, 0, stream>>>(WhT, gi, resets, h0, bhn, ys);
}